// Round 10
// baseline (270.686 us; speedup 1.0000x reference)
//
#include <hip/hip_runtime.h>
#include <math.h>

#define N_TL 131072
#define GRID 4096          // 32 TLs per block
#define BLK 256

typedef __attribute__((ext_vector_type(8))) short bfrag;
typedef __attribute__((ext_vector_type(4))) float f32x4;

// RNE bf16 (weights, staged once)
__device__ __forceinline__ unsigned short f2bf_rne(float x) {
  unsigned int u = __float_as_uint(x);
  return (unsigned short)((u + 0x7fffu + ((u >> 16) & 1u)) >> 16);
}
// round-half-up pack of 2 floats -> bf16x2 via v_perm (3 VALU)
__device__ __forceinline__ unsigned int pack2(float a, float b) {
  return __builtin_amdgcn_perm(__float_as_uint(b) + 0x8000u,
                               __float_as_uint(a) + 0x8000u, 0x07060302u);
}
__device__ __forceinline__ float lo16(unsigned int u) { return __uint_as_float(u << 16); }
__device__ __forceinline__ float hi16(unsigned int u) { return __uint_as_float(u & 0xffff0000u); }
__device__ __forceinline__ f32x4 mfma16(bfrag a, bfrag b, f32x4 c) {
  return __builtin_amdgcn_mfma_f32_16x16x32_bf16(a, b, c, 0, 0, 0);
}
__device__ __forceinline__ f32x4 ldg4(const float* __restrict__ p) {
  return *reinterpret_cast<const f32x4*>(p);
}

// Weight A-fragment (W^T): A[m=col0+(lane&15)][k=k0+quad*8+j] = W[k][col]*scale, 0 for k>=K.
__device__ __forceinline__ bfrag load_wfragT(const float* __restrict__ w, int ncols,
                                             int col0, int k0, int lane, int K, float scale) {
  const int mm = lane & 15, qq = lane >> 4;
  bfrag f;
  #pragma unroll
  for (int j = 0; j < 8; ++j) {
    const int k = k0 + qq * 8 + j;
    const float v = (k < K) ? w[(size_t)k * ncols + col0 + mm] * scale : 0.f;
    f[j] = (short)f2bf_rne(v);
  }
  return f;
}

// B-operand (activations) from row-major bf16 LDS
#define LDBACT(arr, stride, nt, kk) \
  (*reinterpret_cast<const bfrag*>(&(arr)[((nt) * 16 + m) * (stride) + (kk) * 32 + quad * 8]))

// LDS: ~52.7 KB -> 3 blocks/CU
struct alignas(16) SmemF {
  union {
    unsigned short qkv[64 * 200];  // qkv bf16 during A attention (25.6 KB)
    unsigned short h[64 * 136];    // layer1 out bf16 (dead before qkv write)
    unsigned short ph[32 * 136];   // B: pL1 out; head-L1 out (A-part dead)
  };
  unsigned short emb[64 * 72];     // emb; om[16][264] overlays (9.2 KB)
  unsigned short xbuf[64 * 32];    // A layer1 input / B phase-L1 input (4 KB)
  unsigned short feat[32 * 200];   // [ctx(64) | phase_emb(128)] persists A->B (12.8 KB)
  float rbias[4][128];             // head_b1 + region[g] @ head_w1[192:200,:] (2 KB)
  int ridx[32];
};

__global__ __launch_bounds__(BLK, 3)
void fused_policy(const float* __restrict__ queue,
                  const float* __restrict__ waiting,
                  const float* __restrict__ phase_onehot,
                  const float* __restrict__ elapsed,
                  const int* __restrict__ region_ids,
                  const float* __restrict__ noise,
                  const float* __restrict__ lane_w1,
                  const float* __restrict__ lane_b1,
                  const float* __restrict__ lane_w2,
                  const float* __restrict__ lane_b2,
                  const float* __restrict__ attn_in_w,
                  const float* __restrict__ attn_in_b,
                  const float* __restrict__ attn_out_w,
                  const float* __restrict__ attn_out_b,
                  const float* __restrict__ phase_w1,
                  const float* __restrict__ phase_b1,
                  const float* __restrict__ phase_w2,
                  const float* __restrict__ phase_b2,
                  const float* __restrict__ region_table,
                  const float* __restrict__ head_w1,
                  const float* __restrict__ head_b1,
                  const float* __restrict__ head_w2,
                  const float* __restrict__ head_b2,
                  const float* __restrict__ log_std,
                  float* __restrict__ out) {
  __shared__ SmemF S;
  const int tid  = threadIdx.x;
  const int wv   = tid >> 6;
  const int lane = tid & 63;
  const int m    = lane & 15;
  const int quad = lane >> 4;
  const int n0   = blockIdx.x * 32;         // 32 TLs per block

  // ---- A-part register weight fragments (14 frags; B frags loaded AFTER A loop) ----
  bfrag wL1[2], wL2[4], wQKV[3][2], wOUT2[2];
  #pragma unroll
  for (int Mi = 0; Mi < 2; ++Mi)
    wL1[Mi] = load_wfragT(lane_w1, 128, (wv * 2 + Mi) * 16, 0, lane, 3, 1.f);
  #pragma unroll
  for (int kk = 0; kk < 4; ++kk)
    wL2[kk] = load_wfragT(lane_w2, 64, wv * 16, kk * 32, lane, 128, 1.f);
  #pragma unroll
  for (int Mi = 0; Mi < 3; ++Mi)
    #pragma unroll
    for (int kk = 0; kk < 2; ++kk)
      wQKV[Mi][kk] = load_wfragT(attn_in_w, 192, (wv + Mi * 4) * 16, kk * 32, lane, 64,
                                 Mi == 0 ? 0.25f : 1.f);   // fold 1/sqrt(HD) into Q
  // out-proj with query-mean folded: K=256, W'[k][c] = Wout[k&63][c]*0.25 -> 2 distinct frags
  #pragma unroll
  for (int kk = 0; kk < 2; ++kk) {
    bfrag f;
    #pragma unroll
    for (int j = 0; j < 8; ++j) {
      const int k = kk * 32 + quad * 8 + j;
      f[j] = (short)f2bf_rne(attn_out_w[(size_t)k * 64 + wv * 16 + m] * 0.25f);
    }
    wOUT2[kk] = f;
  }

  // ---- per-region folded bias (only LDS-resident table) ----
  for (int i = tid; i < 512; i += BLK) {
    const int g = i >> 7, c = i & 127;
    float acc = head_b1[c];
    #pragma unroll
    for (int j = 0; j < 8; ++j) acc += region_table[g * 8 + j] * head_w1[(192 + j) * 128 + c];
    S.rbias[g][c] = acc;
  }
  if (tid < 32) {
    int r = region_ids[n0 + tid];
    S.ridx[tid] = r < 0 ? 0 : (r > 3 ? 3 : r);
  }
  // stage x for sub-iter 0 (16 TLs x 4 lane-rows, K padded to 32)
  {
    const int r = tid >> 2, seg = tid & 3;
    uint4 z = {0, 0, 0, 0};
    if (seg == 0) {
      const int gl = n0 * 4 + r;
      z.x = pack2(queue[gl], waiting[gl]);
      z.y = pack2(elapsed[n0 + (r >> 2)], 0.f);
    }
    *reinterpret_cast<uint4*>(&S.xbuf[r * 32 + seg * 8]) = z;
  }
  __syncthreads();

  // ================= A-part: 2 sub-iters of 16 TLs =================
  #pragma unroll 1
  for (int s = 0; s < 2; ++s) {
    const int tl0 = n0 + s * 16;

    // ---- layer1 MFMA (K=32 zero-padded): h^T = w1^T @ x, bias (global) in acc-init ----
    {
      f32x4 acc[2][4];
      #pragma unroll
      for (int Mi = 0; Mi < 2; ++Mi) {
        const f32x4 bb = ldg4(&lane_b1[(wv * 2 + Mi) * 16 + quad * 4]);
        #pragma unroll
        for (int Nt = 0; Nt < 4; ++Nt) acc[Mi][Nt] = bb;
      }
      #pragma unroll
      for (int Nt = 0; Nt < 4; ++Nt) {
        const bfrag b = LDBACT(S.xbuf, 32, Nt, 0);
        acc[0][Nt] = mfma16(wL1[0], b, acc[0][Nt]);
        acc[1][Nt] = mfma16(wL1[1], b, acc[1][Nt]);
      }
      #pragma unroll
      for (int Mi = 0; Mi < 2; ++Mi) {
        const int oc0 = (wv * 2 + Mi) * 16 + quad * 4;
        #pragma unroll
        for (int Nt = 0; Nt < 4; ++Nt) {
          const int row = Nt * 16 + m;
          uint2 u;
          u.x = pack2(fmaxf(acc[Mi][Nt][0], 0.f), fmaxf(acc[Mi][Nt][1], 0.f));
          u.y = pack2(fmaxf(acc[Mi][Nt][2], 0.f), fmaxf(acc[Mi][Nt][3], 0.f));
          *reinterpret_cast<uint2*>(&S.h[row * 136 + oc0]) = u;
        }
      }
    }
    __syncthreads();

    // ---- layer2: emb^T = w2^T @ h, bias in acc-init ----
    {
      const int oc0 = wv * 16 + quad * 4;
      const f32x4 bb = ldg4(&lane_b2[oc0]);
      f32x4 acc[4] = {bb, bb, bb, bb};
      #pragma unroll
      for (int Nt = 0; Nt < 4; ++Nt)
        #pragma unroll
        for (int kk = 0; kk < 4; ++kk)
          acc[Nt] = mfma16(wL2[kk], LDBACT(S.h, 136, Nt, kk), acc[Nt]);
      #pragma unroll
      for (int Nt = 0; Nt < 4; ++Nt) {
        const int row = Nt * 16 + m;
        uint2 u;
        u.x = pack2(fmaxf(acc[Nt][0], 0.f), fmaxf(acc[Nt][1], 0.f));
        u.y = pack2(fmaxf(acc[Nt][2], 0.f), fmaxf(acc[Nt][3], 0.f));
        *reinterpret_cast<uint2*>(&S.emb[row * 72 + oc0]) = u;
      }
    }
    __syncthreads();

    // ---- QKV: qkv^T = Win^T @ emb (bf16 out), bias in acc-init; stage next x ----
    {
      f32x4 acc[3][4];
      #pragma unroll
      for (int Mi = 0; Mi < 3; ++Mi) {
        f32x4 bb = ldg4(&attn_in_b[(wv + Mi * 4) * 16 + quad * 4]);
        if (Mi == 0) bb *= 0.25f;     // 1/sqrt(HD) folded into Q
        #pragma unroll
        for (int Nt = 0; Nt < 4; ++Nt) acc[Mi][Nt] = bb;
      }
      #pragma unroll
      for (int Nt = 0; Nt < 4; ++Nt) {
        const bfrag e0 = LDBACT(S.emb, 72, Nt, 0);
        const bfrag e1 = LDBACT(S.emb, 72, Nt, 1);
        #pragma unroll
        for (int Mi = 0; Mi < 3; ++Mi) {
          acc[Mi][Nt] = mfma16(wQKV[Mi][0], e0, acc[Mi][Nt]);
          acc[Mi][Nt] = mfma16(wQKV[Mi][1], e1, acc[Mi][Nt]);
        }
      }
      #pragma unroll
      for (int Mi = 0; Mi < 3; ++Mi) {
        const int oc0 = (wv + Mi * 4) * 16 + quad * 4;
        #pragma unroll
        for (int Nt = 0; Nt < 4; ++Nt) {
          const int row = Nt * 16 + m;
          uint2 u;
          u.x = pack2(acc[Mi][Nt][0], acc[Mi][Nt][1]);
          u.y = pack2(acc[Mi][Nt][2], acc[Mi][Nt][3]);
          *reinterpret_cast<uint2*>(&S.qkv[row * 200 + oc0]) = u;
        }
      }
      const int r = tid >> 2, seg = tid & 3;
      uint4 z = {0, 0, 0, 0};
      if (s == 0) {     // prefetch sub-iter 1's lane inputs
        if (seg == 0) {
          const int gl = (tl0 + 16) * 4 + r;
          z.x = pack2(queue[gl], waiting[gl]);
          z.y = pack2(elapsed[tl0 + 16 + (r >> 2)], 0.f);
        }
      } else {          // stage B phase-L1 input (32 TLs, K padded to 32)
        if (seg == 0 && r < 32) {
          const float4 p = *reinterpret_cast<const float4*>(&phase_onehot[(n0 + r) * 4]);
          z.x = pack2(p.x, p.y);
          z.y = pack2(p.z, p.w);
          z.z = pack2(elapsed[n0 + r], 0.f);
        }
      }
      *reinterpret_cast<uint4*>(&S.xbuf[r * 32 + seg * 8]) = z;
    }
    __syncthreads();

    // ---- attention: 16 threads/TL = 4 heads x 4 queries; uint lo/hi unpack ----
    {
      const int tl = tid >> 4, l16 = tid & 15;
      const int hh = l16 >> 2, lq = l16 & 3;
      const unsigned int* qp = reinterpret_cast<const unsigned int*>(
          &S.qkv[(tl * 4 + lq) * 200 + hh * 16]);
      unsigned int qu[8];
      #pragma unroll
      for (int j = 0; j < 8; ++j) qu[j] = qp[j];
      float qlo[8], qhi[8];
      #pragma unroll
      for (int j = 0; j < 8; ++j) { qlo[j] = lo16(qu[j]); qhi[j] = hi16(qu[j]); }
      float sc[4];
      #pragma unroll
      for (int lk = 0; lk < 4; ++lk) {
        const unsigned int* kp = reinterpret_cast<const unsigned int*>(
            &S.qkv[(tl * 4 + lk) * 200 + 64 + hh * 16]);
        float tx = 0.f, ty = 0.f;
        #pragma unroll
        for (int j = 0; j < 8; ++j) {
          const unsigned int ku = kp[j];
          tx += qlo[j] * lo16(ku);
          ty += qhi[j] * hi16(ku);
        }
        sc[lk] = tx + ty;
      }
      const float mx = fmaxf(fmaxf(sc[0], sc[1]), fmaxf(sc[2], sc[3]));
      const float e0 = __expf(sc[0] - mx), e1 = __expf(sc[1] - mx);
      const float e2 = __expf(sc[2] - mx), e3 = __expf(sc[3] - mx);
      const float inv = 1.f / (e0 + e1 + e2 + e3);
      const float pr[4] = {e0 * inv, e1 * inv, e2 * inv, e3 * inv};
      float olo[8], ohi[8];
      #pragma unroll
      for (int j = 0; j < 8; ++j) { olo[j] = 0.f; ohi[j] = 0.f; }
      #pragma unroll
      for (int lk = 0; lk < 4; ++lk) {
        const unsigned int* vp = reinterpret_cast<const unsigned int*>(
            &S.qkv[(tl * 4 + lk) * 200 + 128 + hh * 16]);
        const float p = pr[lk];
        #pragma unroll
        for (int j = 0; j < 8; ++j) {
          const unsigned int vu = vp[j];
          olo[j] += p * lo16(vu);
          ohi[j] += p * hi16(vu);
        }
      }
      // mean over queries folded into wOUT; raw o -> om[tl][lq*64 + hh*16 + d]
      unsigned short* om = S.emb;
      const int base = tl * 264 + lq * 64 + hh * 16;
      *reinterpret_cast<uint4*>(&om[base]) =
          make_uint4(pack2(olo[0], ohi[0]), pack2(olo[1], ohi[1]),
                     pack2(olo[2], ohi[2]), pack2(olo[3], ohi[3]));
      *reinterpret_cast<uint4*>(&om[base + 8]) =
          make_uint4(pack2(olo[4], ohi[4]), pack2(olo[5], ohi[5]),
                     pack2(olo[6], ohi[6]), pack2(olo[7], ohi[7]));
    }
    __syncthreads();

    // ---- out-proj (K=256, mean folded), bias in acc-init -> feat rows s*16.. ----
    {
      const int oc0 = wv * 16 + quad * 4;
      f32x4 acc = ldg4(&attn_out_b[oc0]);
      #pragma unroll
      for (int kk = 0; kk < 8; ++kk)
        acc = mfma16(wOUT2[kk & 1], LDBACT(S.emb, 264, 0, kk), acc);
      uint2 u;
      u.x = pack2(acc[0], acc[1]);
      u.y = pack2(acc[2], acc[3]);
      *reinterpret_cast<uint2*>(&S.feat[(s * 16 + m) * 200 + oc0]) = u;
    }
    // no barrier: next layer1 writes S.h (attn readers of qkv passed barrier);
    // feat readers are behind the post-loop barrier.
  }
  __syncthreads();

  // ================= B-part: 32 TLs =================
  // B-part weight fragments loaded HERE so their live range does not overlap
  // the A-part fragments (up-front load -> scratch spill, R7).
  __builtin_amdgcn_sched_barrier(0);
  bfrag wP1[2], wP2[2][4], wH1[2][6];
  #pragma unroll
  for (int Mi = 0; Mi < 2; ++Mi) {
    wP1[Mi] = load_wfragT(phase_w1, 128, (wv * 2 + Mi) * 16, 0, lane, 5, 1.f);
    #pragma unroll
    for (int kk = 0; kk < 4; ++kk)
      wP2[Mi][kk] = load_wfragT(phase_w2, 128, (wv * 2 + Mi) * 16, kk * 32, lane, 128, 1.f);
    #pragma unroll
    for (int kk = 0; kk < 6; ++kk)
      wH1[Mi][kk] = load_wfragT(head_w1, 128, (wv * 2 + Mi) * 16, kk * 32, lane, 192, 1.f);
  }

  // ---- phase L1 MFMA (K=32 zero-padded), bias in acc-init -> ph ----
  {
    f32x4 acc[2][2];
    #pragma unroll
    for (int Mi = 0; Mi < 2; ++Mi) {
      const f32x4 bb = ldg4(&phase_b1[(wv * 2 + Mi) * 16 + quad * 4]);
      acc[Mi][0] = bb; acc[Mi][1] = bb;
    }
    #pragma unroll
    for (int Nt = 0; Nt < 2; ++Nt) {
      const bfrag b = LDBACT(S.xbuf, 32, Nt, 0);
      acc[0][Nt] = mfma16(wP1[0], b, acc[0][Nt]);
      acc[1][Nt] = mfma16(wP1[1], b, acc[1][Nt]);
    }
    #pragma unroll
    for (int Mi = 0; Mi < 2; ++Mi) {
      const int oc0 = (wv * 2 + Mi) * 16 + quad * 4;
      #pragma unroll
      for (int Nt = 0; Nt < 2; ++Nt) {
        const int row = Nt * 16 + m;
        uint2 u;
        u.x = pack2(fmaxf(acc[Mi][Nt][0], 0.f), fmaxf(acc[Mi][Nt][1], 0.f));
        u.y = pack2(fmaxf(acc[Mi][Nt][2], 0.f), fmaxf(acc[Mi][Nt][3], 0.f));
        *reinterpret_cast<uint2*>(&S.ph[row * 136 + oc0]) = u;
      }
    }
  }
  __syncthreads();

  // ---- phase L2 (K=128), bias in acc-init -> feat cols 64..191 ----
  {
    f32x4 acc[2][2];
    #pragma unroll
    for (int Mi = 0; Mi < 2; ++Mi) {
      const f32x4 bb = ldg4(&phase_b2[(wv * 2 + Mi) * 16 + quad * 4]);
      acc[Mi][0] = bb; acc[Mi][1] = bb;
    }
    #pragma unroll
    for (int kk = 0; kk < 4; ++kk)
      #pragma unroll
      for (int Nt = 0; Nt < 2; ++Nt) {
        const bfrag b = LDBACT(S.ph, 136, Nt, kk);
        acc[0][Nt] = mfma16(wP2[0][kk], b, acc[0][Nt]);
        acc[1][Nt] = mfma16(wP2[1][kk], b, acc[1][Nt]);
      }
    #pragma unroll
    for (int Mi = 0; Mi < 2; ++Mi) {
      const int oc0 = (wv * 2 + Mi) * 16 + quad * 4;
      #pragma unroll
      for (int Nt = 0; Nt < 2; ++Nt) {
        const int row = Nt * 16 + m;
        uint2 u;
        u.x = pack2(fmaxf(acc[Mi][Nt][0], 0.f), fmaxf(acc[Mi][Nt][1], 0.f));
        u.y = pack2(fmaxf(acc[Mi][Nt][2], 0.f), fmaxf(acc[Mi][Nt][3], 0.f));
        *reinterpret_cast<uint2*>(&S.feat[row * 200 + 64 + oc0]) = u;
      }
    }
  }
  __syncthreads();

  // ---- head L1 (K=192), per-region bias in acc-init -> ph (overlay) ----
  {
    f32x4 acc[2][2];
    #pragma unroll
    for (int Mi = 0; Mi < 2; ++Mi) {
      const int oc0 = (wv * 2 + Mi) * 16 + quad * 4;
      #pragma unroll
      for (int Nt = 0; Nt < 2; ++Nt)
        acc[Mi][Nt] = *reinterpret_cast<const f32x4*>(&S.rbias[S.ridx[Nt * 16 + m]][oc0]);
    }
    #pragma unroll
    for (int kk = 0; kk < 6; ++kk)
      #pragma unroll
      for (int Nt = 0; Nt < 2; ++Nt) {
        const bfrag b = LDBACT(S.feat, 200, Nt, kk);
        acc[0][Nt] = mfma16(wH1[0][kk], b, acc[0][Nt]);
        acc[1][Nt] = mfma16(wH1[1][kk], b, acc[1][Nt]);
      }
    #pragma unroll
    for (int Mi = 0; Mi < 2; ++Mi) {
      const int oc0 = (wv * 2 + Mi) * 16 + quad * 4;
      #pragma unroll
      for (int Nt = 0; Nt < 2; ++Nt) {
        const int row = Nt * 16 + m;
        uint2 u;
        u.x = pack2(fmaxf(acc[Mi][Nt][0], 0.f), fmaxf(acc[Mi][Nt][1], 0.f));
        u.y = pack2(fmaxf(acc[Mi][Nt][2], 0.f), fmaxf(acc[Mi][Nt][3], 0.f));
        *reinterpret_cast<uint2*>(&S.ph[row * 136 + oc0]) = u;
      }
    }
  }
  __syncthreads();

  // ---- head L2 (128->1) + gaussian: 8 threads/TL, hw2 from global (L1-cached) ----
  {
    const int tl = tid >> 3, s8 = tid & 7;   // 32 TLs x 8 threads
    const unsigned int* hp = reinterpret_cast<const unsigned int*>(&S.ph[tl * 136 + s8 * 16]);
    const f32x4 w0 = ldg4(&head_w2[s8 * 16]);
    const f32x4 w1 = ldg4(&head_w2[s8 * 16 + 4]);
    const f32x4 w2 = ldg4(&head_w2[s8 * 16 + 8]);
    const f32x4 w3 = ldg4(&head_w2[s8 * 16 + 12]);
    float wreg[16] = {w0[0], w0[1], w0[2], w0[3], w1[0], w1[1], w1[2], w1[3],
                      w2[0], w2[1], w2[2], w2[3], w3[0], w3[1], w3[2], w3[3]};
    float t = 0.f;
    #pragma unroll
    for (int j = 0; j < 8; ++j) {
      const unsigned int hu = hp[j];
      t += lo16(hu) * wreg[2 * j];
      t += hi16(hu) * wreg[2 * j + 1];
    }
    t += __shfl_xor(t, 1);
    t += __shfl_xor(t, 2);
    t += __shfl_xor(t, 4);
    if (s8 == 0) {
      const int n = n0 + tl;
      const float means = t + head_b2[0];
      const float ls = log_std[0];
      const float nz = noise[n];
      const float a = means + __expf(ls) * nz;
      out[n] = fminf(fmaxf(a, -1.f), 1.f);
      // (actions - means) == std*noise exactly -> log_prob independent of means
      out[N_TL + n] = -0.5f * (nz * nz + 2.f * ls + 1.8378770664093453f);
    }
  }
}

extern "C" void kernel_launch(void* const* d_in, const int* in_sizes, int n_in,
                              void* d_out, int out_size, void* d_ws, size_t ws_size,
                              hipStream_t stream) {
  const float* queue        = (const float*)d_in[0];
  const float* waiting      = (const float*)d_in[1];
  const float* phase_onehot = (const float*)d_in[2];
  const float* elapsed      = (const float*)d_in[3];
  const int*   region_ids   = (const int*)d_in[4];
  const float* noise        = (const float*)d_in[5];
  const float* lane_w1      = (const float*)d_in[6];
  const float* lane_b1      = (const float*)d_in[7];
  const float* lane_w2      = (const float*)d_in[8];
  const float* lane_b2      = (const float*)d_in[9];
  const float* attn_in_w    = (const float*)d_in[10];
  const float* attn_in_b    = (const float*)d_in[11];
  const float* attn_out_w   = (const float*)d_in[12];
  const float* attn_out_b   = (const float*)d_in[13];
  const float* phase_w1     = (const float*)d_in[14];
  const float* phase_b1     = (const float*)d_in[15];
  const float* phase_w2     = (const float*)d_in[16];
  const float* phase_b2     = (const float*)d_in[17];
  const float* region_table = (const float*)d_in[18];
  const float* head_w1      = (const float*)d_in[19];
  const float* head_b1      = (const float*)d_in[20];
  const float* head_w2      = (const float*)d_in[21];
  const float* head_b2      = (const float*)d_in[22];
  const float* log_std      = (const float*)d_in[23];

  float* out = (float*)d_out;
  (void)d_ws; (void)ws_size;

  hipLaunchKernelGGL(fused_policy, dim3(GRID), dim3(BLK), 0, stream,
                     queue, waiting, phase_onehot, elapsed, region_ids, noise,
                     lane_w1, lane_b1, lane_w2, lane_b2,
                     attn_in_w, attn_in_b, attn_out_w, attn_out_b,
                     phase_w1, phase_b1, phase_w2, phase_b2, region_table,
                     head_w1, head_b1, head_w2, head_b2, log_std, out);
}

// Round 11
// 230.221 us; speedup vs baseline: 1.1758x; 1.1758x over previous
//
#include <hip/hip_runtime.h>
#include <math.h>

#define N_TL 131072
#define GRID 4096          // 32 TLs per block
#define BLK 256

typedef __attribute__((ext_vector_type(8))) short bfrag;
typedef __attribute__((ext_vector_type(4))) float f32x4;

// RNE bf16 (weights, staged once)
__device__ __forceinline__ unsigned short f2bf_rne(float x) {
  unsigned int u = __float_as_uint(x);
  return (unsigned short)((u + 0x7fffu + ((u >> 16) & 1u)) >> 16);
}
// round-half-up pack of 2 floats -> bf16x2 via v_perm (3 VALU)
__device__ __forceinline__ unsigned int pack2(float a, float b) {
  return __builtin_amdgcn_perm(__float_as_uint(b) + 0x8000u,
                               __float_as_uint(a) + 0x8000u, 0x07060302u);
}
__device__ __forceinline__ float lo16(unsigned int u) { return __uint_as_float(u << 16); }
__device__ __forceinline__ float hi16(unsigned int u) { return __uint_as_float(u & 0xffff0000u); }
__device__ __forceinline__ f32x4 mfma16(bfrag a, bfrag b, f32x4 c) {
  return __builtin_amdgcn_mfma_f32_16x16x32_bf16(a, b, c, 0, 0, 0);
}
__device__ __forceinline__ f32x4 ldg4(const float* __restrict__ p) {
  return *reinterpret_cast<const f32x4*>(p);
}

// Weight A-fragment (W^T): A[m=col0+(lane&15)][k=k0+quad*8+j] = W[k][col]*scale, 0 for k>=K.
__device__ __forceinline__ bfrag load_wfragT(const float* __restrict__ w, int ncols,
                                             int col0, int k0, int lane, int K, float scale) {
  const int mm = lane & 15, qq = lane >> 4;
  bfrag f;
  #pragma unroll
  for (int j = 0; j < 8; ++j) {
    const int k = k0 + qq * 8 + j;
    const float v = (k < K) ? w[(size_t)k * ncols + col0 + mm] * scale : 0.f;
    f[j] = (short)f2bf_rne(v);
  }
  return f;
}

// B-operand (activations) from row-major bf16 LDS
#define LDBACT(arr, stride, nt, kk) \
  (*reinterpret_cast<const bfrag*>(&(arr)[((nt) * 16 + m) * (stride) + (kk) * 32 + quad * 8]))

// LDS: ~53 KB -> 3 blocks/CU (VGPR must stay <=128: launch_bounds(256,2), R10's
// (256,3) hint capped VGPR at 84 -> 40 MB scratch spill)
struct alignas(16) SmemF {
  union {
    unsigned short qkv[64 * 200];  // qkv bf16 during A attention (25.6 KB)
    unsigned short h[64 * 136];    // layer1 out bf16 (dead before qkv write)
    unsigned short ph[32 * 136];   // B: pL1 out; head-L1 out (A-part dead)
  };
  unsigned short emb[64 * 72];     // emb; om[16][264] overlays (9.2 KB)
  unsigned short xbuf[64 * 32];    // A layer1 input / B phase-L1 input (4 KB)
  unsigned short feat[32 * 200];   // [ctx(64) | phase_emb(128)] persists A->B (12.8 KB)
  float rbias[4][128];             // head_b1 + region[g] @ head_w1[192:200,:] (2 KB)
  int ridx[32];
};

__global__ __launch_bounds__(BLK, 2)
void fused_policy(const float* __restrict__ queue,
                  const float* __restrict__ waiting,
                  const float* __restrict__ phase_onehot,
                  const float* __restrict__ elapsed,
                  const int* __restrict__ region_ids,
                  const float* __restrict__ noise,
                  const float* __restrict__ lane_w1,
                  const float* __restrict__ lane_b1,
                  const float* __restrict__ lane_w2,
                  const float* __restrict__ lane_b2,
                  const float* __restrict__ attn_in_w,
                  const float* __restrict__ attn_in_b,
                  const float* __restrict__ attn_out_w,
                  const float* __restrict__ attn_out_b,
                  const float* __restrict__ phase_w1,
                  const float* __restrict__ phase_b1,
                  const float* __restrict__ phase_w2,
                  const float* __restrict__ phase_b2,
                  const float* __restrict__ region_table,
                  const float* __restrict__ head_w1,
                  const float* __restrict__ head_b1,
                  const float* __restrict__ head_w2,
                  const float* __restrict__ head_b2,
                  const float* __restrict__ log_std,
                  float* __restrict__ out) {
  __shared__ SmemF S;
  const int tid  = threadIdx.x;
  const int wv   = tid >> 6;
  const int lane = tid & 63;
  const int m    = lane & 15;
  const int quad = lane >> 4;
  const int n0   = blockIdx.x * 32;         // 32 TLs per block

  // ---- A-part register weight fragments (14 frags; B frags loaded AFTER A loop) ----
  bfrag wL1[2], wL2[4], wQKV[3][2], wOUT2[2];
  #pragma unroll
  for (int Mi = 0; Mi < 2; ++Mi)
    wL1[Mi] = load_wfragT(lane_w1, 128, (wv * 2 + Mi) * 16, 0, lane, 3, 1.f);
  #pragma unroll
  for (int kk = 0; kk < 4; ++kk)
    wL2[kk] = load_wfragT(lane_w2, 64, wv * 16, kk * 32, lane, 128, 1.f);
  #pragma unroll
  for (int Mi = 0; Mi < 3; ++Mi)
    #pragma unroll
    for (int kk = 0; kk < 2; ++kk)
      wQKV[Mi][kk] = load_wfragT(attn_in_w, 192, (wv + Mi * 4) * 16, kk * 32, lane, 64,
                                 Mi == 0 ? 0.25f : 1.f);   // fold 1/sqrt(HD) into Q
  // out-proj with query-mean folded: K=256, W'[k][c] = Wout[k&63][c]*0.25 -> 2 distinct frags
  #pragma unroll
  for (int kk = 0; kk < 2; ++kk) {
    bfrag f;
    #pragma unroll
    for (int j = 0; j < 8; ++j) {
      const int k = kk * 32 + quad * 8 + j;
      f[j] = (short)f2bf_rne(attn_out_w[(size_t)k * 64 + wv * 16 + m] * 0.25f);
    }
    wOUT2[kk] = f;
  }

  // ---- per-region folded bias (only LDS-resident table) ----
  for (int i = tid; i < 512; i += BLK) {
    const int g = i >> 7, c = i & 127;
    float acc = head_b1[c];
    #pragma unroll
    for (int j = 0; j < 8; ++j) acc += region_table[g * 8 + j] * head_w1[(192 + j) * 128 + c];
    S.rbias[g][c] = acc;
  }
  if (tid < 32) {
    int r = region_ids[n0 + tid];
    S.ridx[tid] = r < 0 ? 0 : (r > 3 ? 3 : r);
  }
  // stage x for sub-iter 0 (16 TLs x 4 lane-rows, K padded to 32)
  {
    const int r = tid >> 2, seg = tid & 3;
    uint4 z = {0, 0, 0, 0};
    if (seg == 0) {
      const int gl = n0 * 4 + r;
      z.x = pack2(queue[gl], waiting[gl]);
      z.y = pack2(elapsed[n0 + (r >> 2)], 0.f);
    }
    *reinterpret_cast<uint4*>(&S.xbuf[r * 32 + seg * 8]) = z;
  }
  __syncthreads();

  // ================= A-part: 2 sub-iters of 16 TLs =================
  #pragma unroll 1
  for (int s = 0; s < 2; ++s) {
    const int tl0 = n0 + s * 16;

    // ---- layer1 MFMA (K=32 zero-padded): h^T = w1^T @ x, bias (global) in acc-init ----
    {
      f32x4 acc[2][4];
      #pragma unroll
      for (int Mi = 0; Mi < 2; ++Mi) {
        const f32x4 bb = ldg4(&lane_b1[(wv * 2 + Mi) * 16 + quad * 4]);
        #pragma unroll
        for (int Nt = 0; Nt < 4; ++Nt) acc[Mi][Nt] = bb;
      }
      #pragma unroll
      for (int Nt = 0; Nt < 4; ++Nt) {
        const bfrag b = LDBACT(S.xbuf, 32, Nt, 0);
        acc[0][Nt] = mfma16(wL1[0], b, acc[0][Nt]);
        acc[1][Nt] = mfma16(wL1[1], b, acc[1][Nt]);
      }
      #pragma unroll
      for (int Mi = 0; Mi < 2; ++Mi) {
        const int oc0 = (wv * 2 + Mi) * 16 + quad * 4;
        #pragma unroll
        for (int Nt = 0; Nt < 4; ++Nt) {
          const int row = Nt * 16 + m;
          uint2 u;
          u.x = pack2(fmaxf(acc[Mi][Nt][0], 0.f), fmaxf(acc[Mi][Nt][1], 0.f));
          u.y = pack2(fmaxf(acc[Mi][Nt][2], 0.f), fmaxf(acc[Mi][Nt][3], 0.f));
          *reinterpret_cast<uint2*>(&S.h[row * 136 + oc0]) = u;
        }
      }
    }
    __syncthreads();

    // ---- layer2: emb^T = w2^T @ h, bias in acc-init ----
    {
      const int oc0 = wv * 16 + quad * 4;
      const f32x4 bb = ldg4(&lane_b2[oc0]);
      f32x4 acc[4] = {bb, bb, bb, bb};
      #pragma unroll
      for (int Nt = 0; Nt < 4; ++Nt)
        #pragma unroll
        for (int kk = 0; kk < 4; ++kk)
          acc[Nt] = mfma16(wL2[kk], LDBACT(S.h, 136, Nt, kk), acc[Nt]);
      #pragma unroll
      for (int Nt = 0; Nt < 4; ++Nt) {
        const int row = Nt * 16 + m;
        uint2 u;
        u.x = pack2(fmaxf(acc[Nt][0], 0.f), fmaxf(acc[Nt][1], 0.f));
        u.y = pack2(fmaxf(acc[Nt][2], 0.f), fmaxf(acc[Nt][3], 0.f));
        *reinterpret_cast<uint2*>(&S.emb[row * 72 + oc0]) = u;
      }
    }
    __syncthreads();

    // ---- QKV: qkv^T = Win^T @ emb (bf16 out), bias in acc-init; stage next x ----
    {
      f32x4 acc[3][4];
      #pragma unroll
      for (int Mi = 0; Mi < 3; ++Mi) {
        f32x4 bb = ldg4(&attn_in_b[(wv + Mi * 4) * 16 + quad * 4]);
        if (Mi == 0) bb *= 0.25f;     // 1/sqrt(HD) folded into Q
        #pragma unroll
        for (int Nt = 0; Nt < 4; ++Nt) acc[Mi][Nt] = bb;
      }
      #pragma unroll
      for (int Nt = 0; Nt < 4; ++Nt) {
        const bfrag e0 = LDBACT(S.emb, 72, Nt, 0);
        const bfrag e1 = LDBACT(S.emb, 72, Nt, 1);
        #pragma unroll
        for (int Mi = 0; Mi < 3; ++Mi) {
          acc[Mi][Nt] = mfma16(wQKV[Mi][0], e0, acc[Mi][Nt]);
          acc[Mi][Nt] = mfma16(wQKV[Mi][1], e1, acc[Mi][Nt]);
        }
      }
      #pragma unroll
      for (int Mi = 0; Mi < 3; ++Mi) {
        const int oc0 = (wv + Mi * 4) * 16 + quad * 4;
        #pragma unroll
        for (int Nt = 0; Nt < 4; ++Nt) {
          const int row = Nt * 16 + m;
          uint2 u;
          u.x = pack2(acc[Mi][Nt][0], acc[Mi][Nt][1]);
          u.y = pack2(acc[Mi][Nt][2], acc[Mi][Nt][3]);
          *reinterpret_cast<uint2*>(&S.qkv[row * 200 + oc0]) = u;
        }
      }
      const int r = tid >> 2, seg = tid & 3;
      uint4 z = {0, 0, 0, 0};
      if (s == 0) {     // prefetch sub-iter 1's lane inputs
        if (seg == 0) {
          const int gl = (tl0 + 16) * 4 + r;
          z.x = pack2(queue[gl], waiting[gl]);
          z.y = pack2(elapsed[tl0 + 16 + (r >> 2)], 0.f);
        }
      } else {          // stage B phase-L1 input (32 TLs, K padded to 32)
        if (seg == 0 && r < 32) {
          const float4 p = *reinterpret_cast<const float4*>(&phase_onehot[(n0 + r) * 4]);
          z.x = pack2(p.x, p.y);
          z.y = pack2(p.z, p.w);
          z.z = pack2(elapsed[n0 + r], 0.f);
        }
      }
      *reinterpret_cast<uint4*>(&S.xbuf[r * 32 + seg * 8]) = z;
    }
    __syncthreads();

    // ---- attention: 16 threads/TL = 4 heads x 4 queries; uint lo/hi unpack ----
    {
      const int tl = tid >> 4, l16 = tid & 15;
      const int hh = l16 >> 2, lq = l16 & 3;
      const unsigned int* qp = reinterpret_cast<const unsigned int*>(
          &S.qkv[(tl * 4 + lq) * 200 + hh * 16]);
      unsigned int qu[8];
      #pragma unroll
      for (int j = 0; j < 8; ++j) qu[j] = qp[j];
      float qlo[8], qhi[8];
      #pragma unroll
      for (int j = 0; j < 8; ++j) { qlo[j] = lo16(qu[j]); qhi[j] = hi16(qu[j]); }
      float sc[4];
      #pragma unroll
      for (int lk = 0; lk < 4; ++lk) {
        const unsigned int* kp = reinterpret_cast<const unsigned int*>(
            &S.qkv[(tl * 4 + lk) * 200 + 64 + hh * 16]);
        float tx = 0.f, ty = 0.f;
        #pragma unroll
        for (int j = 0; j < 8; ++j) {
          const unsigned int ku = kp[j];
          tx += qlo[j] * lo16(ku);
          ty += qhi[j] * hi16(ku);
        }
        sc[lk] = tx + ty;
      }
      const float mx = fmaxf(fmaxf(sc[0], sc[1]), fmaxf(sc[2], sc[3]));
      const float e0 = __expf(sc[0] - mx), e1 = __expf(sc[1] - mx);
      const float e2 = __expf(sc[2] - mx), e3 = __expf(sc[3] - mx);
      const float inv = 1.f / (e0 + e1 + e2 + e3);
      const float pr[4] = {e0 * inv, e1 * inv, e2 * inv, e3 * inv};
      float olo[8], ohi[8];
      #pragma unroll
      for (int j = 0; j < 8; ++j) { olo[j] = 0.f; ohi[j] = 0.f; }
      #pragma unroll
      for (int lk = 0; lk < 4; ++lk) {
        const unsigned int* vp = reinterpret_cast<const unsigned int*>(
            &S.qkv[(tl * 4 + lk) * 200 + 128 + hh * 16]);
        const float p = pr[lk];
        #pragma unroll
        for (int j = 0; j < 8; ++j) {
          const unsigned int vu = vp[j];
          olo[j] += p * lo16(vu);
          ohi[j] += p * hi16(vu);
        }
      }
      // mean over queries folded into wOUT; raw o -> om[tl][lq*64 + hh*16 + d]
      unsigned short* om = S.emb;
      const int base = tl * 264 + lq * 64 + hh * 16;
      *reinterpret_cast<uint4*>(&om[base]) =
          make_uint4(pack2(olo[0], ohi[0]), pack2(olo[1], ohi[1]),
                     pack2(olo[2], ohi[2]), pack2(olo[3], ohi[3]));
      *reinterpret_cast<uint4*>(&om[base + 8]) =
          make_uint4(pack2(olo[4], ohi[4]), pack2(olo[5], ohi[5]),
                     pack2(olo[6], ohi[6]), pack2(olo[7], ohi[7]));
    }
    __syncthreads();

    // ---- out-proj (K=256, mean folded), bias in acc-init -> feat rows s*16.. ----
    {
      const int oc0 = wv * 16 + quad * 4;
      f32x4 acc = ldg4(&attn_out_b[oc0]);
      #pragma unroll
      for (int kk = 0; kk < 8; ++kk)
        acc = mfma16(wOUT2[kk & 1], LDBACT(S.emb, 264, 0, kk), acc);
      uint2 u;
      u.x = pack2(acc[0], acc[1]);
      u.y = pack2(acc[2], acc[3]);
      *reinterpret_cast<uint2*>(&S.feat[(s * 16 + m) * 200 + oc0]) = u;
    }
    // no barrier: next layer1 writes S.h (attn readers of qkv passed barrier);
    // feat readers are behind the post-loop barrier.
  }
  __syncthreads();

  // ================= B-part: 32 TLs =================
  // B-part weight fragments loaded HERE so their live range does not overlap
  // the A-part fragments (up-front load -> scratch spill, R7).
  __builtin_amdgcn_sched_barrier(0);
  bfrag wP1[2], wP2[2][4], wH1[2][6];
  #pragma unroll
  for (int Mi = 0; Mi < 2; ++Mi) {
    wP1[Mi] = load_wfragT(phase_w1, 128, (wv * 2 + Mi) * 16, 0, lane, 5, 1.f);
    #pragma unroll
    for (int kk = 0; kk < 4; ++kk)
      wP2[Mi][kk] = load_wfragT(phase_w2, 128, (wv * 2 + Mi) * 16, kk * 32, lane, 128, 1.f);
    #pragma unroll
    for (int kk = 0; kk < 6; ++kk)
      wH1[Mi][kk] = load_wfragT(head_w1, 128, (wv * 2 + Mi) * 16, kk * 32, lane, 192, 1.f);
  }

  // ---- phase L1 MFMA (K=32 zero-padded), bias in acc-init -> ph ----
  {
    f32x4 acc[2][2];
    #pragma unroll
    for (int Mi = 0; Mi < 2; ++Mi) {
      const f32x4 bb = ldg4(&phase_b1[(wv * 2 + Mi) * 16 + quad * 4]);
      acc[Mi][0] = bb; acc[Mi][1] = bb;
    }
    #pragma unroll
    for (int Nt = 0; Nt < 2; ++Nt) {
      const bfrag b = LDBACT(S.xbuf, 32, Nt, 0);
      acc[0][Nt] = mfma16(wP1[0], b, acc[0][Nt]);
      acc[1][Nt] = mfma16(wP1[1], b, acc[1][Nt]);
    }
    #pragma unroll
    for (int Mi = 0; Mi < 2; ++Mi) {
      const int oc0 = (wv * 2 + Mi) * 16 + quad * 4;
      #pragma unroll
      for (int Nt = 0; Nt < 2; ++Nt) {
        const int row = Nt * 16 + m;
        uint2 u;
        u.x = pack2(fmaxf(acc[Mi][Nt][0], 0.f), fmaxf(acc[Mi][Nt][1], 0.f));
        u.y = pack2(fmaxf(acc[Mi][Nt][2], 0.f), fmaxf(acc[Mi][Nt][3], 0.f));
        *reinterpret_cast<uint2*>(&S.ph[row * 136 + oc0]) = u;
      }
    }
  }
  __syncthreads();

  // ---- phase L2 (K=128), bias in acc-init -> feat cols 64..191 ----
  {
    f32x4 acc[2][2];
    #pragma unroll
    for (int Mi = 0; Mi < 2; ++Mi) {
      const f32x4 bb = ldg4(&phase_b2[(wv * 2 + Mi) * 16 + quad * 4]);
      acc[Mi][0] = bb; acc[Mi][1] = bb;
    }
    #pragma unroll
    for (int kk = 0; kk < 4; ++kk)
      #pragma unroll
      for (int Nt = 0; Nt < 2; ++Nt) {
        const bfrag b = LDBACT(S.ph, 136, Nt, kk);
        acc[0][Nt] = mfma16(wP2[0][kk], b, acc[0][Nt]);
        acc[1][Nt] = mfma16(wP2[1][kk], b, acc[1][Nt]);
      }
    #pragma unroll
    for (int Mi = 0; Mi < 2; ++Mi) {
      const int oc0 = (wv * 2 + Mi) * 16 + quad * 4;
      #pragma unroll
      for (int Nt = 0; Nt < 2; ++Nt) {
        const int row = Nt * 16 + m;
        uint2 u;
        u.x = pack2(fmaxf(acc[Mi][Nt][0], 0.f), fmaxf(acc[Mi][Nt][1], 0.f));
        u.y = pack2(fmaxf(acc[Mi][Nt][2], 0.f), fmaxf(acc[Mi][Nt][3], 0.f));
        *reinterpret_cast<uint2*>(&S.feat[row * 200 + 64 + oc0]) = u;
      }
    }
  }
  __syncthreads();

  // ---- head L1 (K=192), per-region bias in acc-init -> ph (overlay) ----
  {
    f32x4 acc[2][2];
    #pragma unroll
    for (int Mi = 0; Mi < 2; ++Mi) {
      const int oc0 = (wv * 2 + Mi) * 16 + quad * 4;
      #pragma unroll
      for (int Nt = 0; Nt < 2; ++Nt)
        acc[Mi][Nt] = *reinterpret_cast<const f32x4*>(&S.rbias[S.ridx[Nt * 16 + m]][oc0]);
    }
    #pragma unroll
    for (int kk = 0; kk < 6; ++kk)
      #pragma unroll
      for (int Nt = 0; Nt < 2; ++Nt) {
        const bfrag b = LDBACT(S.feat, 200, Nt, kk);
        acc[0][Nt] = mfma16(wH1[0][kk], b, acc[0][Nt]);
        acc[1][Nt] = mfma16(wH1[1][kk], b, acc[1][Nt]);
      }
    #pragma unroll
    for (int Mi = 0; Mi < 2; ++Mi) {
      const int oc0 = (wv * 2 + Mi) * 16 + quad * 4;
      #pragma unroll
      for (int Nt = 0; Nt < 2; ++Nt) {
        const int row = Nt * 16 + m;
        uint2 u;
        u.x = pack2(fmaxf(acc[Mi][Nt][0], 0.f), fmaxf(acc[Mi][Nt][1], 0.f));
        u.y = pack2(fmaxf(acc[Mi][Nt][2], 0.f), fmaxf(acc[Mi][Nt][3], 0.f));
        *reinterpret_cast<uint2*>(&S.ph[row * 136 + oc0]) = u;
      }
    }
  }
  __syncthreads();

  // ---- head L2 (128->1) + gaussian: 8 threads/TL, hw2 from global (L1-cached) ----
  {
    const int tl = tid >> 3, s8 = tid & 7;   // 32 TLs x 8 threads
    const unsigned int* hp = reinterpret_cast<const unsigned int*>(&S.ph[tl * 136 + s8 * 16]);
    const f32x4 w0 = ldg4(&head_w2[s8 * 16]);
    const f32x4 w1 = ldg4(&head_w2[s8 * 16 + 4]);
    const f32x4 w2 = ldg4(&head_w2[s8 * 16 + 8]);
    const f32x4 w3 = ldg4(&head_w2[s8 * 16 + 12]);
    float wreg[16] = {w0[0], w0[1], w0[2], w0[3], w1[0], w1[1], w1[2], w1[3],
                      w2[0], w2[1], w2[2], w2[3], w3[0], w3[1], w3[2], w3[3]};
    float t = 0.f;
    #pragma unroll
    for (int j = 0; j < 8; ++j) {
      const unsigned int hu = hp[j];
      t += lo16(hu) * wreg[2 * j];
      t += hi16(hu) * wreg[2 * j + 1];
    }
    t += __shfl_xor(t, 1);
    t += __shfl_xor(t, 2);
    t += __shfl_xor(t, 4);
    if (s8 == 0) {
      const int n = n0 + tl;
      const float means = t + head_b2[0];
      const float ls = log_std[0];
      const float nz = noise[n];
      const float a = means + __expf(ls) * nz;
      out[n] = fminf(fmaxf(a, -1.f), 1.f);
      // (actions - means) == std*noise exactly -> log_prob independent of means
      out[N_TL + n] = -0.5f * (nz * nz + 2.f * ls + 1.8378770664093453f);
    }
  }
}

extern "C" void kernel_launch(void* const* d_in, const int* in_sizes, int n_in,
                              void* d_out, int out_size, void* d_ws, size_t ws_size,
                              hipStream_t stream) {
  const float* queue        = (const float*)d_in[0];
  const float* waiting      = (const float*)d_in[1];
  const float* phase_onehot = (const float*)d_in[2];
  const float* elapsed      = (const float*)d_in[3];
  const int*   region_ids   = (const int*)d_in[4];
  const float* noise        = (const float*)d_in[5];
  const float* lane_w1      = (const float*)d_in[6];
  const float* lane_b1      = (const float*)d_in[7];
  const float* lane_w2      = (const float*)d_in[8];
  const float* lane_b2      = (const float*)d_in[9];
  const float* attn_in_w    = (const float*)d_in[10];
  const float* attn_in_b    = (const float*)d_in[11];
  const float* attn_out_w   = (const float*)d_in[12];
  const float* attn_out_b   = (const float*)d_in[13];
  const float* phase_w1     = (const float*)d_in[14];
  const float* phase_b1     = (const float*)d_in[15];
  const float* phase_w2     = (const float*)d_in[16];
  const float* phase_b2     = (const float*)d_in[17];
  const float* region_table = (const float*)d_in[18];
  const float* head_w1      = (const float*)d_in[19];
  const float* head_b1      = (const float*)d_in[20];
  const float* head_w2      = (const float*)d_in[21];
  const float* head_b2      = (const float*)d_in[22];
  const float* log_std      = (const float*)d_in[23];

  float* out = (float*)d_out;
  (void)d_ws; (void)ws_size;

  hipLaunchKernelGGL(fused_policy, dim3(GRID), dim3(BLK), 0, stream,
                     queue, waiting, phase_onehot, elapsed, region_ids, noise,
                     lane_w1, lane_b1, lane_w2, lane_b2,
                     attn_in_w, attn_in_b, attn_out_w, attn_out_b,
                     phase_w1, phase_b1, phase_w2, phase_b2, region_table,
                     head_w1, head_b1, head_w2, head_b2, log_std, out);
}

// Round 12
// 202.506 us; speedup vs baseline: 1.3367x; 1.1369x over previous
//
#include <hip/hip_runtime.h>
#include <math.h>

#define N_TL 131072
#define GRID 2048          // 64 TLs per block (R9 shape: measured-best)
#define BLK 256

typedef __attribute__((ext_vector_type(8))) short bfrag;
typedef __attribute__((ext_vector_type(4))) float f32x4;

// RNE bf16 (weights, staged once)
__device__ __forceinline__ unsigned short f2bf_rne(float x) {
  unsigned int u = __float_as_uint(x);
  return (unsigned short)((u + 0x7fffu + ((u >> 16) & 1u)) >> 16);
}
// round-half-up pack of 2 floats -> bf16x2 via v_perm (3 VALU)
__device__ __forceinline__ unsigned int pack2(float a, float b) {
  return __builtin_amdgcn_perm(__float_as_uint(b) + 0x8000u,
                               __float_as_uint(a) + 0x8000u, 0x07060302u);
}
__device__ __forceinline__ float lo16(unsigned int u) { return __uint_as_float(u << 16); }
__device__ __forceinline__ float hi16(unsigned int u) { return __uint_as_float(u & 0xffff0000u); }
__device__ __forceinline__ f32x4 mfma16(bfrag a, bfrag b, f32x4 c) {
  return __builtin_amdgcn_mfma_f32_16x16x32_bf16(a, b, c, 0, 0, 0);
}
__device__ __forceinline__ f32x4 ldg4(const float* __restrict__ p) {
  return *reinterpret_cast<const f32x4*>(p);
}

// Weight A-fragment (W^T): A[m=col0+(lane&15)][k=k0+quad*8+j] = W[k][col]*scale, 0 for k>=K.
__device__ __forceinline__ bfrag load_wfragT(const float* __restrict__ w, int ncols,
                                             int col0, int k0, int lane, int K, float scale) {
  const int mm = lane & 15, qq = lane >> 4;
  bfrag f;
  #pragma unroll
  for (int j = 0; j < 8; ++j) {
    const int k = k0 + qq * 8 + j;
    const float v = (k < K) ? w[(size_t)k * ncols + col0 + mm] * scale : 0.f;
    f[j] = (short)f2bf_rne(v);
  }
  return f;
}

// B-operand (activations) from row-major bf16 LDS
#define LDBACT(arr, stride, nt, kk) \
  (*reinterpret_cast<const bfrag*>(&(arr)[((nt) * 16 + m) * (stride) + (kk) * 32 + quad * 8]))

// LDS: ~67 KB -> 2 blocks/CU (R10/R11: 3-block diet at 32 TLs regressed —
// thinner barrier phases at unchanged residency; 64 TLs is the local optimum)
struct alignas(16) SmemF {
  union {
    unsigned short qkv[64 * 200];  // qkv bf16 during A attention (25.6 KB)
    unsigned short h[64 * 136];    // layer1 out bf16 (dead before qkv write)
    unsigned short ph[64 * 136];   // B: pL1 out; head-L1 out (A-part dead)
  };
  unsigned short emb[64 * 72];     // emb; om[16][264] overlays (9.2 KB)
  unsigned short xbuf[64 * 32];    // A layer1 input / B phase-L1 input (4 KB)
  unsigned short feat[64 * 200];   // [ctx(64) | phase_emb(128)] persists A->B (25.6 KB)
  float rbias[4][128];             // head_b1 + region[g] @ head_w1[192:200,:] (2 KB)
  int ridx[64];
};

__global__ __launch_bounds__(BLK, 2)
void fused_policy(const float* __restrict__ queue,
                  const float* __restrict__ waiting,
                  const float* __restrict__ phase_onehot,
                  const float* __restrict__ elapsed,
                  const int* __restrict__ region_ids,
                  const float* __restrict__ noise,
                  const float* __restrict__ lane_w1,
                  const float* __restrict__ lane_b1,
                  const float* __restrict__ lane_w2,
                  const float* __restrict__ lane_b2,
                  const float* __restrict__ attn_in_w,
                  const float* __restrict__ attn_in_b,
                  const float* __restrict__ attn_out_w,
                  const float* __restrict__ attn_out_b,
                  const float* __restrict__ phase_w1,
                  const float* __restrict__ phase_b1,
                  const float* __restrict__ phase_w2,
                  const float* __restrict__ phase_b2,
                  const float* __restrict__ region_table,
                  const float* __restrict__ head_w1,
                  const float* __restrict__ head_b1,
                  const float* __restrict__ head_w2,
                  const float* __restrict__ head_b2,
                  const float* __restrict__ log_std,
                  float* __restrict__ out) {
  __shared__ SmemF S;
  const int tid  = threadIdx.x;
  const int wv   = tid >> 6;
  const int lane = tid & 63;
  const int m    = lane & 15;
  const int quad = lane >> 4;
  const int n0   = blockIdx.x * 64;         // 64 TLs per block

  // ---- A-part register weight fragments (14 frags; B frags loaded AFTER A loop) ----
  bfrag wL1[2], wL2[4], wQKV[3][2], wOUT2[2];
  #pragma unroll
  for (int Mi = 0; Mi < 2; ++Mi)
    wL1[Mi] = load_wfragT(lane_w1, 128, (wv * 2 + Mi) * 16, 0, lane, 3, 1.f);
  #pragma unroll
  for (int kk = 0; kk < 4; ++kk)
    wL2[kk] = load_wfragT(lane_w2, 64, wv * 16, kk * 32, lane, 128, 1.f);
  #pragma unroll
  for (int Mi = 0; Mi < 3; ++Mi)
    #pragma unroll
    for (int kk = 0; kk < 2; ++kk)
      wQKV[Mi][kk] = load_wfragT(attn_in_w, 192, (wv + Mi * 4) * 16, kk * 32, lane, 64,
                                 Mi == 0 ? 0.25f : 1.f);   // fold 1/sqrt(HD) into Q
  // out-proj with query-mean folded: K=256, W'[k][c] = Wout[k&63][c]*0.25 -> 2 distinct frags
  #pragma unroll
  for (int kk = 0; kk < 2; ++kk) {
    bfrag f;
    #pragma unroll
    for (int j = 0; j < 8; ++j) {
      const int k = kk * 32 + quad * 8 + j;
      f[j] = (short)f2bf_rne(attn_out_w[(size_t)k * 64 + wv * 16 + m] * 0.25f);
    }
    wOUT2[kk] = f;
  }

  // ---- per-region folded bias (only LDS-resident table) ----
  for (int i = tid; i < 512; i += BLK) {
    const int g = i >> 7, c = i & 127;
    float acc = head_b1[c];
    #pragma unroll
    for (int j = 0; j < 8; ++j) acc += region_table[g * 8 + j] * head_w1[(192 + j) * 128 + c];
    S.rbias[g][c] = acc;
  }
  if (tid < 64) {
    int r = region_ids[n0 + tid];
    S.ridx[tid] = r < 0 ? 0 : (r > 3 ? 3 : r);
  }
  // stage x for sub-iter 0 (16 TLs x 4 lane-rows, K padded to 32)
  {
    const int r = tid >> 2, seg = tid & 3;
    uint4 z = {0, 0, 0, 0};
    if (seg == 0) {
      const int gl = n0 * 4 + r;
      z.x = pack2(queue[gl], waiting[gl]);
      z.y = pack2(elapsed[n0 + (r >> 2)], 0.f);
    }
    *reinterpret_cast<uint4*>(&S.xbuf[r * 32 + seg * 8]) = z;
  }
  __syncthreads();

  // ================= A-part: 4 sub-iters of 16 TLs =================
  #pragma unroll 1
  for (int s = 0; s < 4; ++s) {
    const int tl0 = n0 + s * 16;

    // ---- layer1 MFMA (K=32 zero-padded): h^T = w1^T @ x, bias (global) in acc-init ----
    {
      f32x4 acc[2][4];
      #pragma unroll
      for (int Mi = 0; Mi < 2; ++Mi) {
        const f32x4 bb = ldg4(&lane_b1[(wv * 2 + Mi) * 16 + quad * 4]);
        #pragma unroll
        for (int Nt = 0; Nt < 4; ++Nt) acc[Mi][Nt] = bb;
      }
      #pragma unroll
      for (int Nt = 0; Nt < 4; ++Nt) {
        const bfrag b = LDBACT(S.xbuf, 32, Nt, 0);
        acc[0][Nt] = mfma16(wL1[0], b, acc[0][Nt]);
        acc[1][Nt] = mfma16(wL1[1], b, acc[1][Nt]);
      }
      #pragma unroll
      for (int Mi = 0; Mi < 2; ++Mi) {
        const int oc0 = (wv * 2 + Mi) * 16 + quad * 4;
        #pragma unroll
        for (int Nt = 0; Nt < 4; ++Nt) {
          const int row = Nt * 16 + m;
          uint2 u;
          u.x = pack2(fmaxf(acc[Mi][Nt][0], 0.f), fmaxf(acc[Mi][Nt][1], 0.f));
          u.y = pack2(fmaxf(acc[Mi][Nt][2], 0.f), fmaxf(acc[Mi][Nt][3], 0.f));
          *reinterpret_cast<uint2*>(&S.h[row * 136 + oc0]) = u;
        }
      }
    }
    __syncthreads();

    // ---- layer2: emb^T = w2^T @ h, bias in acc-init ----
    {
      const int oc0 = wv * 16 + quad * 4;
      const f32x4 bb = ldg4(&lane_b2[oc0]);
      f32x4 acc[4] = {bb, bb, bb, bb};
      #pragma unroll
      for (int Nt = 0; Nt < 4; ++Nt)
        #pragma unroll
        for (int kk = 0; kk < 4; ++kk)
          acc[Nt] = mfma16(wL2[kk], LDBACT(S.h, 136, Nt, kk), acc[Nt]);
      #pragma unroll
      for (int Nt = 0; Nt < 4; ++Nt) {
        const int row = Nt * 16 + m;
        uint2 u;
        u.x = pack2(fmaxf(acc[Nt][0], 0.f), fmaxf(acc[Nt][1], 0.f));
        u.y = pack2(fmaxf(acc[Nt][2], 0.f), fmaxf(acc[Nt][3], 0.f));
        *reinterpret_cast<uint2*>(&S.emb[row * 72 + oc0]) = u;
      }
    }
    __syncthreads();

    // ---- QKV: qkv^T = Win^T @ emb (bf16 out), bias in acc-init; stage next x ----
    {
      f32x4 acc[3][4];
      #pragma unroll
      for (int Mi = 0; Mi < 3; ++Mi) {
        f32x4 bb = ldg4(&attn_in_b[(wv + Mi * 4) * 16 + quad * 4]);
        if (Mi == 0) bb *= 0.25f;     // 1/sqrt(HD) folded into Q
        #pragma unroll
        for (int Nt = 0; Nt < 4; ++Nt) acc[Mi][Nt] = bb;
      }
      #pragma unroll
      for (int Nt = 0; Nt < 4; ++Nt) {
        const bfrag e0 = LDBACT(S.emb, 72, Nt, 0);
        const bfrag e1 = LDBACT(S.emb, 72, Nt, 1);
        #pragma unroll
        for (int Mi = 0; Mi < 3; ++Mi) {
          acc[Mi][Nt] = mfma16(wQKV[Mi][0], e0, acc[Mi][Nt]);
          acc[Mi][Nt] = mfma16(wQKV[Mi][1], e1, acc[Mi][Nt]);
        }
      }
      #pragma unroll
      for (int Mi = 0; Mi < 3; ++Mi) {
        const int oc0 = (wv + Mi * 4) * 16 + quad * 4;
        #pragma unroll
        for (int Nt = 0; Nt < 4; ++Nt) {
          const int row = Nt * 16 + m;
          uint2 u;
          u.x = pack2(acc[Mi][Nt][0], acc[Mi][Nt][1]);
          u.y = pack2(acc[Mi][Nt][2], acc[Mi][Nt][3]);
          *reinterpret_cast<uint2*>(&S.qkv[row * 200 + oc0]) = u;
        }
      }
      const int r = tid >> 2, seg = tid & 3;
      uint4 z = {0, 0, 0, 0};
      if (s < 3) {      // prefetch next sub-iter's lane inputs
        if (seg == 0) {
          const int gl = (tl0 + 16) * 4 + r;
          z.x = pack2(queue[gl], waiting[gl]);
          z.y = pack2(elapsed[tl0 + 16 + (r >> 2)], 0.f);
        }
      } else {          // stage B phase-L1 input (64 TLs, K padded to 32)
        if (seg == 0) {
          const float4 p = *reinterpret_cast<const float4*>(&phase_onehot[(n0 + r) * 4]);
          z.x = pack2(p.x, p.y);
          z.y = pack2(p.z, p.w);
          z.z = pack2(elapsed[n0 + r], 0.f);
        }
      }
      *reinterpret_cast<uint4*>(&S.xbuf[r * 32 + seg * 8]) = z;
    }
    __syncthreads();

    // ---- attention: 16 threads/TL = 4 heads x 4 queries; uint lo/hi unpack ----
    {
      const int tl = tid >> 4, l16 = tid & 15;
      const int hh = l16 >> 2, lq = l16 & 3;
      const unsigned int* qp = reinterpret_cast<const unsigned int*>(
          &S.qkv[(tl * 4 + lq) * 200 + hh * 16]);
      unsigned int qu[8];
      #pragma unroll
      for (int j = 0; j < 8; ++j) qu[j] = qp[j];
      float qlo[8], qhi[8];
      #pragma unroll
      for (int j = 0; j < 8; ++j) { qlo[j] = lo16(qu[j]); qhi[j] = hi16(qu[j]); }
      float sc[4];
      #pragma unroll
      for (int lk = 0; lk < 4; ++lk) {
        const unsigned int* kp = reinterpret_cast<const unsigned int*>(
            &S.qkv[(tl * 4 + lk) * 200 + 64 + hh * 16]);
        float tx = 0.f, ty = 0.f;
        #pragma unroll
        for (int j = 0; j < 8; ++j) {
          const unsigned int ku = kp[j];
          tx += qlo[j] * lo16(ku);
          ty += qhi[j] * hi16(ku);
        }
        sc[lk] = tx + ty;
      }
      const float mx = fmaxf(fmaxf(sc[0], sc[1]), fmaxf(sc[2], sc[3]));
      const float e0 = __expf(sc[0] - mx), e1 = __expf(sc[1] - mx);
      const float e2 = __expf(sc[2] - mx), e3 = __expf(sc[3] - mx);
      const float inv = 1.f / (e0 + e1 + e2 + e3);
      const float pr[4] = {e0 * inv, e1 * inv, e2 * inv, e3 * inv};
      float olo[8], ohi[8];
      #pragma unroll
      for (int j = 0; j < 8; ++j) { olo[j] = 0.f; ohi[j] = 0.f; }
      #pragma unroll
      for (int lk = 0; lk < 4; ++lk) {
        const unsigned int* vp = reinterpret_cast<const unsigned int*>(
            &S.qkv[(tl * 4 + lk) * 200 + 128 + hh * 16]);
        const float p = pr[lk];
        #pragma unroll
        for (int j = 0; j < 8; ++j) {
          const unsigned int vu = vp[j];
          olo[j] += p * lo16(vu);
          ohi[j] += p * hi16(vu);
        }
      }
      // mean over queries folded into wOUT; raw o -> om[tl][lq*64 + hh*16 + d]
      unsigned short* om = S.emb;
      const int base = tl * 264 + lq * 64 + hh * 16;
      *reinterpret_cast<uint4*>(&om[base]) =
          make_uint4(pack2(olo[0], ohi[0]), pack2(olo[1], ohi[1]),
                     pack2(olo[2], ohi[2]), pack2(olo[3], ohi[3]));
      *reinterpret_cast<uint4*>(&om[base + 8]) =
          make_uint4(pack2(olo[4], ohi[4]), pack2(olo[5], ohi[5]),
                     pack2(olo[6], ohi[6]), pack2(olo[7], ohi[7]));
    }
    __syncthreads();

    // ---- out-proj (K=256, mean folded), bias in acc-init -> feat rows s*16.. ----
    {
      const int oc0 = wv * 16 + quad * 4;
      f32x4 acc = ldg4(&attn_out_b[oc0]);
      #pragma unroll
      for (int kk = 0; kk < 8; ++kk)
        acc = mfma16(wOUT2[kk & 1], LDBACT(S.emb, 264, 0, kk), acc);
      uint2 u;
      u.x = pack2(acc[0], acc[1]);
      u.y = pack2(acc[2], acc[3]);
      *reinterpret_cast<uint2*>(&S.feat[(s * 16 + m) * 200 + oc0]) = u;
    }
    // no barrier: next layer1 writes S.h (attn readers of qkv passed barrier);
    // feat readers are behind the post-loop barrier.
  }
  __syncthreads();

  // ================= B-part: 64 TLs =================
  // B-part weight fragments loaded HERE so their live range does not overlap
  // the A-part fragments (up-front load -> scratch spill, R7).
  __builtin_amdgcn_sched_barrier(0);
  bfrag wP1[2], wP2[2][4], wH1[2][6];
  #pragma unroll
  for (int Mi = 0; Mi < 2; ++Mi) {
    wP1[Mi] = load_wfragT(phase_w1, 128, (wv * 2 + Mi) * 16, 0, lane, 5, 1.f);
    #pragma unroll
    for (int kk = 0; kk < 4; ++kk)
      wP2[Mi][kk] = load_wfragT(phase_w2, 128, (wv * 2 + Mi) * 16, kk * 32, lane, 128, 1.f);
    #pragma unroll
    for (int kk = 0; kk < 6; ++kk)
      wH1[Mi][kk] = load_wfragT(head_w1, 128, (wv * 2 + Mi) * 16, kk * 32, lane, 192, 1.f);
  }

  // ---- phase L1 MFMA (K=32 zero-padded), bias in acc-init -> ph ----
  {
    f32x4 acc[2][4];
    #pragma unroll
    for (int Mi = 0; Mi < 2; ++Mi) {
      const f32x4 bb = ldg4(&phase_b1[(wv * 2 + Mi) * 16 + quad * 4]);
      #pragma unroll
      for (int Nt = 0; Nt < 4; ++Nt) acc[Mi][Nt] = bb;
    }
    #pragma unroll
    for (int Nt = 0; Nt < 4; ++Nt) {
      const bfrag b = LDBACT(S.xbuf, 32, Nt, 0);
      acc[0][Nt] = mfma16(wP1[0], b, acc[0][Nt]);
      acc[1][Nt] = mfma16(wP1[1], b, acc[1][Nt]);
    }
    #pragma unroll
    for (int Mi = 0; Mi < 2; ++Mi) {
      const int oc0 = (wv * 2 + Mi) * 16 + quad * 4;
      #pragma unroll
      for (int Nt = 0; Nt < 4; ++Nt) {
        const int row = Nt * 16 + m;
        uint2 u;
        u.x = pack2(fmaxf(acc[Mi][Nt][0], 0.f), fmaxf(acc[Mi][Nt][1], 0.f));
        u.y = pack2(fmaxf(acc[Mi][Nt][2], 0.f), fmaxf(acc[Mi][Nt][3], 0.f));
        *reinterpret_cast<uint2*>(&S.ph[row * 136 + oc0]) = u;
      }
    }
  }
  __syncthreads();

  // ---- phase L2 (K=128), bias in acc-init -> feat cols 64..191 ----
  {
    f32x4 acc[2][4];
    #pragma unroll
    for (int Mi = 0; Mi < 2; ++Mi) {
      const f32x4 bb = ldg4(&phase_b2[(wv * 2 + Mi) * 16 + quad * 4]);
      #pragma unroll
      for (int Nt = 0; Nt < 4; ++Nt) acc[Mi][Nt] = bb;
    }
    #pragma unroll
    for (int kk = 0; kk < 4; ++kk)
      #pragma unroll
      for (int Nt = 0; Nt < 4; ++Nt) {
        const bfrag b = LDBACT(S.ph, 136, Nt, kk);
        acc[0][Nt] = mfma16(wP2[0][kk], b, acc[0][Nt]);
        acc[1][Nt] = mfma16(wP2[1][kk], b, acc[1][Nt]);
      }
    #pragma unroll
    for (int Mi = 0; Mi < 2; ++Mi) {
      const int oc0 = (wv * 2 + Mi) * 16 + quad * 4;
      #pragma unroll
      for (int Nt = 0; Nt < 4; ++Nt) {
        const int row = Nt * 16 + m;
        uint2 u;
        u.x = pack2(fmaxf(acc[Mi][Nt][0], 0.f), fmaxf(acc[Mi][Nt][1], 0.f));
        u.y = pack2(fmaxf(acc[Mi][Nt][2], 0.f), fmaxf(acc[Mi][Nt][3], 0.f));
        *reinterpret_cast<uint2*>(&S.feat[row * 200 + 64 + oc0]) = u;
      }
    }
  }
  __syncthreads();

  // ---- head L1 (K=192), per-region bias in acc-init -> ph (overlay) ----
  {
    f32x4 acc[2][4];
    #pragma unroll
    for (int Mi = 0; Mi < 2; ++Mi) {
      const int oc0 = (wv * 2 + Mi) * 16 + quad * 4;
      #pragma unroll
      for (int Nt = 0; Nt < 4; ++Nt)
        acc[Mi][Nt] = *reinterpret_cast<const f32x4*>(&S.rbias[S.ridx[Nt * 16 + m]][oc0]);
    }
    #pragma unroll
    for (int kk = 0; kk < 6; ++kk)
      #pragma unroll
      for (int Nt = 0; Nt < 4; ++Nt) {
        const bfrag b = LDBACT(S.feat, 200, Nt, kk);
        acc[0][Nt] = mfma16(wH1[0][kk], b, acc[0][Nt]);
        acc[1][Nt] = mfma16(wH1[1][kk], b, acc[1][Nt]);
      }
    #pragma unroll
    for (int Mi = 0; Mi < 2; ++Mi) {
      const int oc0 = (wv * 2 + Mi) * 16 + quad * 4;
      #pragma unroll
      for (int Nt = 0; Nt < 4; ++Nt) {
        const int row = Nt * 16 + m;
        uint2 u;
        u.x = pack2(fmaxf(acc[Mi][Nt][0], 0.f), fmaxf(acc[Mi][Nt][1], 0.f));
        u.y = pack2(fmaxf(acc[Mi][Nt][2], 0.f), fmaxf(acc[Mi][Nt][3], 0.f));
        *reinterpret_cast<uint2*>(&S.ph[row * 136 + oc0]) = u;
      }
    }
  }
  __syncthreads();

  // ---- head L2 (128->1) + gaussian: 4 threads/TL, hw2 from global (L1-cached) ----
  {
    const int tl = tid >> 2, s4 = tid & 3;   // 64 TLs x 4 threads
    const unsigned int* hp = reinterpret_cast<const unsigned int*>(&S.ph[tl * 136 + s4 * 32]);
    f32x4 w[8];
    #pragma unroll
    for (int i = 0; i < 8; ++i) w[i] = ldg4(&head_w2[s4 * 32 + i * 4]);
    float t = 0.f;
    #pragma unroll
    for (int j = 0; j < 16; ++j) {
      const unsigned int hu = hp[j];
      t += lo16(hu) * w[j >> 1][(j & 1) * 2];
      t += hi16(hu) * w[j >> 1][(j & 1) * 2 + 1];
    }
    t += __shfl_xor(t, 1);
    t += __shfl_xor(t, 2);
    if (s4 == 0) {
      const int n = n0 + tl;
      const float means = t + head_b2[0];
      const float ls = log_std[0];
      const float nz = noise[n];
      const float a = means + __expf(ls) * nz;
      out[n] = fminf(fmaxf(a, -1.f), 1.f);
      // (actions - means) == std*noise exactly -> log_prob independent of means
      out[N_TL + n] = -0.5f * (nz * nz + 2.f * ls + 1.8378770664093453f);
    }
  }
}

extern "C" void kernel_launch(void* const* d_in, const int* in_sizes, int n_in,
                              void* d_out, int out_size, void* d_ws, size_t ws_size,
                              hipStream_t stream) {
  const float* queue        = (const float*)d_in[0];
  const float* waiting      = (const float*)d_in[1];
  const float* phase_onehot = (const float*)d_in[2];
  const float* elapsed      = (const float*)d_in[3];
  const int*   region_ids   = (const int*)d_in[4];
  const float* noise        = (const float*)d_in[5];
  const float* lane_w1      = (const float*)d_in[6];
  const float* lane_b1      = (const float*)d_in[7];
  const float* lane_w2      = (const float*)d_in[8];
  const float* lane_b2      = (const float*)d_in[9];
  const float* attn_in_w    = (const float*)d_in[10];
  const float* attn_in_b    = (const float*)d_in[11];
  const float* attn_out_w   = (const float*)d_in[12];
  const float* attn_out_b   = (const float*)d_in[13];
  const float* phase_w1     = (const float*)d_in[14];
  const float* phase_b1     = (const float*)d_in[15];
  const float* phase_w2     = (const float*)d_in[16];
  const float* phase_b2     = (const float*)d_in[17];
  const float* region_table = (const float*)d_in[18];
  const float* head_w1      = (const float*)d_in[19];
  const float* head_b1      = (const float*)d_in[20];
  const float* head_w2      = (const float*)d_in[21];
  const float* head_b2      = (const float*)d_in[22];
  const float* log_std      = (const float*)d_in[23];

  float* out = (float*)d_out;
  (void)d_ws; (void)ws_size;

  hipLaunchKernelGGL(fused_policy, dim3(GRID), dim3(BLK), 0, stream,
                     queue, waiting, phase_onehot, elapsed, region_ids, noise,
                     lane_w1, lane_b1, lane_w2, lane_b2,
                     attn_in_w, attn_in_b, attn_out_w, attn_out_b,
                     phase_w1, phase_b1, phase_w2, phase_b2, region_table,
                     head_w1, head_b1, head_w2, head_b2, log_std, out);
}